// Round 6
// baseline (340.576 us; speedup 1.0000x reference)
//
#include <hip/hip_runtime.h>
#include <hip/hip_bf16.h>

#define GRIDW 480
#define CELLS_PER_B (GRIDW*GRIDW)       // 230400
#define NCELL (4*CELLS_PER_B)           // 921600
#define NPTS  400000
#define NPB   100000
#define H1D 128
#define H2D 256
#define DD 64
#define SCAN_BLK 900                    // NCELL / 1024
#define NTILE 6250                      // NPTS/64
#define GRIDP 512                       // persistent blocks (2 per CU)
#define NSUB  25000                     // NPTS/16 subtiles (16 sorted pts each)

typedef unsigned short u16;
typedef __attribute__((ext_vector_type(8))) short bf16x8;
typedef __attribute__((ext_vector_type(4))) short s16x4;
typedef __attribute__((ext_vector_type(4))) float f32x4;
typedef __attribute__((ext_vector_type(4))) unsigned u32x4;
typedef __attribute__((ext_vector_type(2))) unsigned u32x2;

// order-preserving float->uint key (fallback path only)
static __device__ __forceinline__ unsigned fkey(float f){
  unsigned u = __float_as_uint(f);
  return (u & 0x80000000u) ? ~u : (u | 0x80000000u);
}
static __device__ __forceinline__ float fdec(unsigned k){
  unsigned u = (k & 0x80000000u) ? (k ^ 0x80000000u) : ~k;
  return __uint_as_float(u);
}
// float -> bf16 bits, round-nearest-even (finite inputs)
static __device__ __forceinline__ u16 f2bf(float f){
  unsigned u = __float_as_uint(f);
  unsigned r = u + 0x7FFFu + ((u>>16)&1u);
  return (u16)(r>>16);
}
static __device__ __forceinline__ float bf2f(u16 b){
  return __uint_as_float(((unsigned)b) << 16);
}
// packed 2x f32 -> 2x bf16 in one u32 (low = first operand)
static __device__ __forceinline__ unsigned cvt_pk_bf16(float lo, float hi){
  unsigned r;
  asm("v_cvt_pk_bf16_f32 %0, %1, %2" : "=v"(r) : "v"(lo), "v"(hi));
  return r;
}

__global__ void k_count(const int* __restrict__ xy, unsigned* __restrict__ counts){
  int p = blockIdx.x*256 + threadIdx.x;
  if (p >= NPTS) return;
  int b = p / NPB;
  int x = xy[2*p], y = xy[2*p+1];
  atomicAdd(&counts[(b*GRIDW + x)*GRIDW + y], 1u);
}

// dual scan: rankF = excl prefix of (count>0), rankC = excl prefix of count
__global__ void k_scan2(const unsigned* __restrict__ counts,
                        unsigned* __restrict__ rankF, unsigned* __restrict__ rankC,
                        unsigned* __restrict__ bsumF, unsigned* __restrict__ bsumC){
  __shared__ unsigned shF[256], shC[256];
  int tid = threadIdx.x;
  int base = blockIdx.x*1024 + tid*4;
  unsigned c0=counts[base], c1=counts[base+1], c2=counts[base+2], c3=counts[base+3];
  unsigned f0=c0?1u:0u, f1=c1?1u:0u, f2=c2?1u:0u, f3=c3?1u:0u;
  unsigned sF=f0+f1+f2+f3, sC=c0+c1+c2+c3;
  shF[tid]=sF; shC[tid]=sC; __syncthreads();
  for (int off=1; off<256; off<<=1){
    unsigned tF = (tid>=off) ? shF[tid-off] : 0u;
    unsigned tC = (tid>=off) ? shC[tid-off] : 0u;
    __syncthreads();
    shF[tid] += tF; shC[tid] += tC;
    __syncthreads();
  }
  unsigned eF = shF[tid]-sF, eC = shC[tid]-sC;
  if (tid==255){ bsumF[blockIdx.x]=shF[255]; bsumC[blockIdx.x]=shC[255]; }
  rankF[base]=eF; rankF[base+1]=eF+f0; rankF[base+2]=eF+f0+f1; rankF[base+3]=eF+f0+f1+f2;
  rankC[base]=eC; rankC[base+1]=eC+c0; rankC[base+2]=eC+c0+c1; rankC[base+3]=eC+c0+c1+c2;
}

__global__ void k_scan_bsum2(unsigned* __restrict__ bsumF, unsigned* __restrict__ bsumC){
  __shared__ unsigned shF[1024], shC[1024];
  int tid = threadIdx.x;
  unsigned vF = (tid<SCAN_BLK) ? bsumF[tid] : 0u;
  unsigned vC = (tid<SCAN_BLK) ? bsumC[tid] : 0u;
  shF[tid]=vF; shC[tid]=vC; __syncthreads();
  for (int off=1; off<1024; off<<=1){
    unsigned tF = (tid>=off) ? shF[tid-off] : 0u;
    unsigned tC = (tid>=off) ? shC[tid-off] : 0u;
    __syncthreads();
    shF[tid] += tF; shC[tid] += tC;
    __syncthreads();
  }
  if (tid<SCAN_BLK){ bsumF[tid]=shF[tid]-vF; bsumC[tid]=shC[tid]-vC; }
}

// finalize ranks, emit unq
__global__ void k_emit2(const unsigned* __restrict__ counts,
                        unsigned* __restrict__ rankF, unsigned* __restrict__ rankC,
                        const unsigned* __restrict__ bsumF, const unsigned* __restrict__ bsumC,
                        float* __restrict__ out){
  int i = blockIdx.x*256 + threadIdx.x;
  if (i >= NCELL) return;
  unsigned rF = rankF[i] + bsumF[i>>10];
  unsigned rC = rankC[i] + bsumC[i>>10];
  rankF[i] = rF;                      // per-cell output rank (voxel id)
  rankC[i] = rC;                      // per-cell scatter cursor
  unsigned c = counts[i];
  if (c){
    int b = i / CELLS_PER_B;
    int rem = i - b*CELLS_PER_B;
    int x = rem / GRIDW;
    int y = rem - x*GRIDW;
    float* o = out + 3u*rF;           // unq written as floats (harness reads f32)
    o[0]=(float)b; o[1]=(float)x; o[2]=(float)y;
  }
}

// scatter point permutation (sorted-by-cell) + per-slot voxel id
__global__ void k_scatterp(const int* __restrict__ xy, unsigned* __restrict__ cursor,
                           const unsigned* __restrict__ rankF,
                           unsigned* __restrict__ perm, unsigned* __restrict__ vox){
  int p = blockIdx.x*256 + threadIdx.x;
  if (p >= NPTS) return;
  int b = p / NPB;
  int x = xy[2*p], y = xy[2*p+1];
  int cell = (b*GRIDW+x)*GRIDW + y;
  unsigned slot = atomicAdd(&cursor[cell], 1u);
  perm[slot] = (unsigned)p;
  vox[slot]  = rankF[cell];
}

__global__ void k_init_pooled(unsigned* __restrict__ pooled, int n){
  for (int i = blockIdx.x*256+threadIdx.x; i < n; i += gridDim.x*256)
    pooled[i] = 0u;
}

__global__ void k_decode(unsigned* __restrict__ pooled, int n){
  for (int i = blockIdx.x*256+threadIdx.x; i < n; i += gridDim.x*256)
    ((float*)pooled)[i] = fdec(pooled[i]);
}

// Pack W2 (128x256) and W3 (256x64) into bf16 MFMA-fragment order:
// bp[((n*KO + ko)*16 + c)*8 + j] = W[(ko*8+j)*N + n*16 + c]
__global__ void k_pack(const float* __restrict__ W2, const float* __restrict__ W3,
                       u16* __restrict__ bp2, u16* __restrict__ bp3){
  int e = blockIdx.x*256 + threadIdx.x;
  if (e < 32768){
    int j = e & 7, c = (e>>3)&15, ko = (e>>7)&15, n = e>>11;   // KO2=16, NT2=16
    bp2[e] = f2bf(W2[(ko*8+j)*H2D + n*16 + c]);
  } else {
    int e3 = e - 32768;
    if (e3 < 16384){
      int j = e3 & 7, c = (e3>>3)&15, ko = (e3>>7)&31, n = e3>>12; // KO3=32, NT3=4
      bp3[e3] = f2bf(W3[(ko*8+j)*DD + n*16 + c]);
    }
  }
}

// ---------------------------------------------------------------------------
// Persistent fused MLP + segmented-max pooling.
// 512 blocks (2/CU), 4 waves; points consumed in voxel-sorted order (perm).
// Epilogue: LDS transpose -> per-wave 16-row run-max -> interior runs stored
// final to out; edge runs -> bf16 partials fixed up by k_fixup. No atomics.
// ---------------------------------------------------------------------------
__global__ __launch_bounds__(256,2) void k_mlpp(
    const float* __restrict__ pt, const unsigned* __restrict__ perm,
    const unsigned* __restrict__ vox,
    const u16* __restrict__ bp2, const u16* __restrict__ bp3,
    const float* __restrict__ W1, const float* __restrict__ b1,
    const float* __restrict__ b2, const float* __restrict__ b3,
    float* __restrict__ outp,
    unsigned* __restrict__ pvf, unsigned* __restrict__ pvl,
    u16* __restrict__ pmf, u16* __restrict__ pml)
{
  __shared__ __attribute__((aligned(16))) u16 h1s[64*128];     // 16 KB, swizzled
  __shared__ __attribute__((aligned(16))) u16 h2s[2][64*64];   // 2x8 KB, swizzled
  __shared__ __attribute__((aligned(16))) float in_s[192];
  __shared__ unsigned vox_s[64];

  const int tid  = threadIdx.x;
  const int lane = tid & 63;
  const int w    = tid >> 6;          // wave 0..3
  const int g    = lane >> 4;         // lane group 0..3
  const int p    = lane & 15;         // lane-in-group
  const int wn   = w & 1;             // col-pair selector
  const int wp   = w >> 1;            // point-pair selector
  const int oct  = tid & 15;          // layer-1 channel octet

  // ---- persistent register state -----------------------------------------
  bf16x8 wf2[32];
  #pragma unroll
  for (int c=0;c<4;++c)
    #pragma unroll
    for (int nn=0;nn<2;++nn)
      #pragma unroll
      for (int t=0;t<4;++t){
        int ngl = c*4 + 2*wn + nn;
        wf2[(c*2+nn)*4+t] = *(const bf16x8*)(bp2 + (((ngl*16 + t*4 + g)*16) + p)*8);
      }
  bf16x8 wf3[16];
  #pragma unroll
  for (int c=0;c<4;++c)
    #pragma unroll
    for (int t2=0;t2<2;++t2)
      #pragma unroll
      for (int dn=0;dn<2;++dn){
        int s = c*2+t2, dt = 2*wn+dn;
        wf3[(c*2+t2)*2+dn] = *(const bf16x8*)(bp3 + (((dt*32 + s*4 + g)*16) + p)*8);
      }
  f32x4 W1p[3][2], b1p[2];
  #pragma unroll
  for (int f=0;f<3;++f){
    W1p[f][0] = *(const f32x4*)(W1 + f*H1D + oct*8);
    W1p[f][1] = *(const f32x4*)(W1 + f*H1D + oct*8 + 4);
  }
  b1p[0] = *(const f32x4*)(b1 + oct*8);
  b1p[1] = *(const f32x4*)(b1 + oct*8 + 4);
  f32x4 b2p[4][2];
  #pragma unroll
  for (int c=0;c<4;++c)
    #pragma unroll
    for (int nn=0;nn<2;++nn)
      b2p[c][nn] = *(const f32x4*)(b2 + c*64 + (2*wn+nn)*16 + g*4);
  f32x4 b3p[2];
  #pragma unroll
  for (int dn=0;dn<2;++dn)
    b3p[dn] = *(const f32x4*)(b3 + (2*wn+dn)*16 + g*4);

  // ---- prologue prefetch: perm + gathered pt for first tile --------------
  int tile = blockIdx.x;
  unsigned pmC = 0, pmN = 0;
  if (tid < 64) pmC = perm[(size_t)tile*64 + tid];
  if (tid < 64 && tile + GRIDP < NTILE) pmN = perm[(size_t)(tile+GRIDP)*64 + tid];
  float pf0=0.f, pf1=0.f, pf2=0.f;
  if (tid < 64){
    const float* q = pt + 3*(size_t)pmC;
    pf0 = q[0]; pf1 = q[1]; pf2 = q[2];
  }

  for (; tile < NTILE; tile += GRIDP){
    if (tid < 64){ in_s[tid*3]=pf0; in_s[tid*3+1]=pf1; in_s[tid*3+2]=pf2; }
    unsigned vr = 0;
    if (tid < 64) vr = vox[(size_t)tile*64 + tid];
    __syncthreads();                                   // A
    // prefetch next tile's points (via pmN) and next-next perm
    if (tid < 64 && tile + GRIDP < NTILE){
      const float* q = pt + 3*(size_t)pmN;
      pf0 = q[0]; pf1 = q[1]; pf2 = q[2];
    }
    unsigned pmN2 = 0;
    if (tid < 64 && tile + 2*GRIDP < NTILE)
      pmN2 = perm[(size_t)(tile+2*GRIDP)*64 + tid];

    // ---- layer 1: h1[64][128] -> bf16 LDS (swizzled) ----
    #pragma unroll
    for (int q=0;q<4;++q){
      int row = q*16 + (tid>>4);
      float x0 = in_s[row*3+0], x1 = in_s[row*3+1], x2 = in_s[row*3+2];
      f32x4 a0 = b1p[0], a1 = b1p[1];
      #pragma unroll
      for (int i=0;i<4;++i){
        a0[i] = fmaf(x0, W1p[0][0][i], a0[i]);
        a1[i] = fmaf(x0, W1p[0][1][i], a1[i]);
        a0[i] = fmaf(x1, W1p[1][0][i], a0[i]);
        a1[i] = fmaf(x1, W1p[1][1][i], a1[i]);
        a0[i] = fmaf(x2, W1p[2][0][i], a0[i]);
        a1[i] = fmaf(x2, W1p[2][1][i], a1[i]);
        a0[i] = fmaxf(a0[i], 0.f);
        a1[i] = fmaxf(a1[i], 0.f);
      }
      u32x4 ov;
      ov[0] = cvt_pk_bf16(a0[0], a0[1]);
      ov[1] = cvt_pk_bf16(a0[2], a0[3]);
      ov[2] = cvt_pk_bf16(a1[0], a1[1]);
      ov[3] = cvt_pk_bf16(a1[2], a1[3]);
      unsigned byte = ((unsigned)row<<8) + (unsigned)oct*16u;
      byte ^= (unsigned)(row&7) << 4;
      *(u32x4*)((char*)h1s + byte) = ov;
    }
    if (tid < 64) vox_s[tid] = vr;
    __syncthreads();                                   // B

    // ---- hoist this wave's h1 fragments ----
    bf16x8 hf[2][4];
    #pragma unroll
    for (int pp=0;pp<2;++pp){
      int row = (2*wp+pp)*16 + p;
      #pragma unroll
      for (int t=0;t<4;++t){
        unsigned byte = ((unsigned)row<<8) + (unsigned)t*64u + (unsigned)g*16u;
        byte ^= (unsigned)(row&7) << 4;
        hf[pp][t] = *(const bf16x8*)((const char*)h1s + byte);
      }
    }

    f32x4 acc3[2][2];
    #pragma unroll
    for (int a=0;a<2;++a)
      #pragma unroll
      for (int b=0;b<2;++b){ acc3[a][b][0]=0.f; acc3[a][b][1]=0.f; acc3[a][b][2]=0.f; acc3[a][b][3]=0.f; }

    // ---- chunk loop over h2 columns (4 x 64) ----
    #pragma unroll
    for (int c=0;c<4;++c){
      f32x4 acc2[2][2];
      #pragma unroll
      for (int a=0;a<2;++a)
        #pragma unroll
        for (int b=0;b<2;++b){ acc2[a][b][0]=0.f; acc2[a][b][1]=0.f; acc2[a][b][2]=0.f; acc2[a][b][3]=0.f; }
      #pragma unroll
      for (int t=0;t<4;++t)
        #pragma unroll
        for (int nn=0;nn<2;++nn)
          #pragma unroll
          for (int pp=0;pp<2;++pp)
            acc2[nn][pp] = __builtin_amdgcn_mfma_f32_16x16x32_bf16(
                wf2[(c*2+nn)*4+t], hf[pp][t], acc2[nn][pp], 0, 0, 0);
      u16* h2 = h2s[c & 1];
      #pragma unroll
      for (int nn=0;nn<2;++nn)
        #pragma unroll
        for (int pp=0;pp<2;++pp){
          int point = (2*wp+pp)*16 + p;
          float e0 = fmaxf(acc2[nn][pp][0] + b2p[c][nn][0], 0.f);
          float e1 = fmaxf(acc2[nn][pp][1] + b2p[c][nn][1], 0.f);
          float e2 = fmaxf(acc2[nn][pp][2] + b2p[c][nn][2], 0.f);
          float e3 = fmaxf(acc2[nn][pp][3] + b2p[c][nn][3], 0.f);
          u32x2 o2; o2[0] = cvt_pk_bf16(e0, e1); o2[1] = cvt_pk_bf16(e2, e3);
          unsigned byte = (unsigned)point*128u + (unsigned)((2*wn+nn)*32 + g*8);
          byte ^= (unsigned)(point&7) << 4;
          *(u32x2*)((char*)h2 + byte) = o2;
        }
      __syncthreads();                                 // C(c)
      #pragma unroll
      for (int t2=0;t2<2;++t2){
        bf16x8 h2f[2];
        #pragma unroll
        for (int pp=0;pp<2;++pp){
          int point = (2*wp+pp)*16 + p;
          unsigned byte = (unsigned)point*128u + (unsigned)t2*64u + (unsigned)g*16u;
          byte ^= (unsigned)(point&7) << 4;
          h2f[pp] = *(const bf16x8*)((const char*)h2 + byte);
        }
        #pragma unroll
        for (int dn=0;dn<2;++dn)
          #pragma unroll
          for (int pp=0;pp<2;++pp)
            acc3[dn][pp] = __builtin_amdgcn_mfma_f32_16x16x32_bf16(
                wf3[(c*2+t2)*2+dn], h2f[pp], acc3[dn][pp], 0, 0, 0);
      }
    }

    // ---- epilogue 1: +b3, transpose into h2s[0] ----
    #pragma unroll
    for (int dn=0;dn<2;++dn)
      #pragma unroll
      for (int pp=0;pp<2;++pp){
        int point = (2*wp+pp)*16 + p;
        float e0 = acc3[dn][pp][0] + b3p[dn][0];
        float e1 = acc3[dn][pp][1] + b3p[dn][1];
        float e2 = acc3[dn][pp][2] + b3p[dn][2];
        float e3 = acc3[dn][pp][3] + b3p[dn][3];
        u32x2 o2; o2[0] = cvt_pk_bf16(e0, e1); o2[1] = cvt_pk_bf16(e2, e3);
        unsigned byte = (unsigned)point*128u + (unsigned)((2*wn+dn)*32 + g*8);
        byte ^= (unsigned)(point&7) << 4;
        *(u32x2*)((char*)h2s[0] + byte) = o2;
      }
    __syncthreads();                                   // E

    // ---- epilogue 2: per-wave segmented max over its 16 sorted rows ----
    {
      int st = tile*4 + w;                             // subtile id
      float val[16]; unsigned vid[16];
      #pragma unroll
      for (int r=0;r<16;++r){
        int row = w*16 + r;
        unsigned byte = (unsigned)row*128u + (unsigned)lane*2u;
        byte ^= (unsigned)(row&7) << 4;
        val[r] = bf2f(*(const u16*)((const char*)h2s[0] + byte));
        vid[r] = vox_s[row];
      }
      float m = val[0];
      unsigned vprev = vid[0];
      int runstart = 0;
      #pragma unroll
      for (int r=1;r<16;++r){
        if (vid[r] != vprev){
          if (runstart == 0){
            pmf[(size_t)st*64 + lane] = (u16)(__float_as_uint(m)>>16);
            if (lane==0) pvf[st] = vprev;
          } else {
            outp[(size_t)vprev*64 + lane] = m;         // interior run: final
          }
          m = val[r]; runstart = r; vprev = vid[r];
        } else m = fmaxf(m, val[r]);
      }
      pml[(size_t)st*64 + lane] = (u16)(__float_as_uint(m)>>16);
      if (lane==0) pvl[st] = vprev;
      if (runstart == 0){                              // whole-subtile run
        pmf[(size_t)st*64 + lane] = (u16)(__float_as_uint(m)>>16);
        if (lane==0) pvf[st] = vprev;
      }
    }
    __syncthreads();                                   // protect LDS reuse
    pmN = pmN2;
  }
}

// resolve subtile-boundary voxel chains (max is idempotent -> safe overlap)
__global__ __launch_bounds__(256) void k_fixup(
    const unsigned* __restrict__ pvf, const unsigned* __restrict__ pvl,
    const u16* __restrict__ pmf, const u16* __restrict__ pml,
    float* __restrict__ outp){
  int t  = blockIdx.x*4 + (threadIdx.x>>6);
  int ch = threadIdx.x & 63;
  if (t >= NSUB) return;
  unsigned vf = pvf[t], vl = pvl[t];
  // case A: chain starting at this subtile's FIRST run
  if (t == 0 || pvl[t-1] != vf){
    float m = bf2f(pmf[(size_t)t*64 + ch]);
    if (vl == vf){
      m = fmaxf(m, bf2f(pml[(size_t)t*64 + ch]));
      int k = t+1;
      while (k < NSUB && pvf[k] == vf){
        m = fmaxf(m, bf2f(pmf[(size_t)k*64 + ch]));
        if (pvl[k] != vf) break;
        m = fmaxf(m, bf2f(pml[(size_t)k*64 + ch]));
        ++k;
      }
    }
    outp[(size_t)vf*64 + ch] = m;
  }
  // case B: chain starting at this subtile's LAST run (born mid-subtile)
  if (vl != vf){
    float m = bf2f(pml[(size_t)t*64 + ch]);
    int k = t+1;
    while (k < NSUB && pvf[k] == vl){
      m = fmaxf(m, bf2f(pmf[(size_t)k*64 + ch]));
      if (pvl[k] != vl) break;
      m = fmaxf(m, bf2f(pml[(size_t)k*64 + ch]));
      ++k;
    }
    outp[(size_t)vl*64 + ch] = m;
  }
}

// fallback (ws too small): fused MLP + fkey atomics
__global__ __launch_bounds__(256,4) void k_mlp_atomic(
    const float* __restrict__ pt, const int* __restrict__ xy,
    const float* __restrict__ W1, const float* __restrict__ b1,
    const u16* __restrict__ bp2, const float* __restrict__ b2,
    const u16* __restrict__ bp3, const float* __restrict__ b3,
    const unsigned* __restrict__ rank, unsigned* __restrict__ pooled)
{
  __shared__ __attribute__((aligned(16))) u16 h1s[64*128];
  __shared__ __attribute__((aligned(16))) u16 h2s[2][64*64];
  __shared__ float    in_s[64][3];
  __shared__ unsigned r_s[64];
  const int tid=threadIdx.x, lane=tid&63, w=tid>>6, g=lane>>4, p=lane&15;
  const int wn=w&1, wp=w>>1, p0g=blockIdx.x*64;
  if (tid < 64){
    int pg = p0g + tid;
    int b = pg / NPB;
    int x = xy[2*pg], y = xy[2*pg+1];
    r_s[tid] = rank[(b*GRIDW+x)*GRIDW + y];
    in_s[tid][0]=pt[pg*3+0]; in_s[tid][1]=pt[pg*3+1]; in_s[tid][2]=pt[pg*3+2];
  }
  __syncthreads();
  #pragma unroll
  for (int q=0;q<4;++q){
    int u = q*256 + tid;
    int row = u >> 4, oct = u & 15;
    float x0=in_s[row][0], x1=in_s[row][1], x2=in_s[row][2];
    bf16x8 ov;
    #pragma unroll
    for (int jj=0;jj<8;++jj){
      int j = oct*8 + jj;
      float v = b1[j] + x0*W1[j] + x1*W1[H1D+j] + x2*W1[2*H1D+j];
      ov[jj] = (short)f2bf(fmaxf(v, 0.f));
    }
    unsigned byte = ((unsigned)row<<8) + (unsigned)oct*16u;
    byte ^= (unsigned)(row&7) << 4;
    *(bf16x8*)((char*)h1s + byte) = ov;
  }
  __syncthreads();
  bf16x8 hf[2][4];
  #pragma unroll
  for (int pp=0;pp<2;++pp){
    int row = (2*wp+pp)*16 + p;
    #pragma unroll
    for (int t=0;t<4;++t){
      unsigned byte = ((unsigned)row<<8) + (unsigned)t*64u + (unsigned)g*16u;
      byte ^= (unsigned)(row&7) << 4;
      hf[pp][t] = *(const bf16x8*)((const char*)h1s + byte);
    }
  }
  f32x4 acc3[2][2];
  #pragma unroll
  for (int a=0;a<2;++a)
    #pragma unroll
    for (int b=0;b<2;++b){ acc3[a][b][0]=0.f; acc3[a][b][1]=0.f; acc3[a][b][2]=0.f; acc3[a][b][3]=0.f; }
  for (int c=0;c<4;++c){
    f32x4 acc2[2][2];
    #pragma unroll
    for (int a=0;a<2;++a)
      #pragma unroll
      for (int b=0;b<2;++b){ acc2[a][b][0]=0.f; acc2[a][b][1]=0.f; acc2[a][b][2]=0.f; acc2[a][b][3]=0.f; }
    #pragma unroll
    for (int t=0;t<4;++t){
      bf16x8 wf[2];
      #pragma unroll
      for (int nn=0;nn<2;++nn){
        int ngl = c*4 + 2*wn + nn;
        wf[nn] = *(const bf16x8*)(bp2 + (((ngl*16 + t*4 + g)*16) + p)*8);
      }
      #pragma unroll
      for (int nn=0;nn<2;++nn)
        #pragma unroll
        for (int pp=0;pp<2;++pp)
          acc2[nn][pp] = __builtin_amdgcn_mfma_f32_16x16x32_bf16(wf[nn], hf[pp][t], acc2[nn][pp], 0, 0, 0);
    }
    u16* h2 = h2s[c & 1];
    #pragma unroll
    for (int nn=0;nn<2;++nn){
      int nb = (2*wn+nn)*16 + g*4;
      f32x4 bb = *(const f32x4*)&b2[c*64 + nb];
      #pragma unroll
      for (int pp=0;pp<2;++pp){
        int point = (2*wp+pp)*16 + p;
        s16x4 o;
        #pragma unroll
        for (int i=0;i<4;++i) o[i] = (short)f2bf(fmaxf(acc2[nn][pp][i] + bb[i], 0.f));
        unsigned byte = (unsigned)point*128u + (unsigned)nb*2u;
        byte ^= (unsigned)(point&7) << 4;
        *(s16x4*)((char*)h2 + byte) = o;
      }
    }
    __syncthreads();
    #pragma unroll
    for (int t2=0;t2<2;++t2){
      int s = c*2 + t2;
      bf16x8 w3f[2], h2f[2];
      #pragma unroll
      for (int dn=0;dn<2;++dn){
        int dt = 2*wn + dn;
        w3f[dn] = *(const bf16x8*)(bp3 + (((dt*32 + s*4 + g)*16) + p)*8);
      }
      #pragma unroll
      for (int pp=0;pp<2;++pp){
        int point = (2*wp+pp)*16 + p;
        unsigned byte = (unsigned)point*128u + (unsigned)t2*64u + (unsigned)g*16u;
        byte ^= (unsigned)(point&7) << 4;
        h2f[pp] = *(const bf16x8*)((const char*)h2 + byte);
      }
      #pragma unroll
      for (int dn=0;dn<2;++dn)
        #pragma unroll
        for (int pp=0;pp<2;++pp)
          acc3[dn][pp] = __builtin_amdgcn_mfma_f32_16x16x32_bf16(w3f[dn], h2f[pp], acc3[dn][pp], 0, 0, 0);
    }
  }
  #pragma unroll
  for (int dn=0;dn<2;++dn){
    int db = (2*wn+dn)*16 + g*4;
    f32x4 b3v = *(const f32x4*)&b3[db];
    #pragma unroll
    for (int pp=0;pp<2;++pp){
      int point = (2*wp+pp)*16 + p;
      unsigned base = r_s[point]*64u + (unsigned)db;
      #pragma unroll
      for (int i=0;i<4;++i)
        atomicMax(&pooled[base + i], fkey(acc3[dn][pp][i] + b3v[i]));
    }
  }
}

extern "C" void kernel_launch(void* const* d_in, const int* in_sizes, int n_in,
                              void* d_out, int out_size, void* d_ws, size_t ws_size,
                              hipStream_t stream){
  const float* pt = (const float*)d_in[0];
  const int*   xy = (const int*)d_in[1];
  const float* W1 = (const float*)d_in[2];
  const float* b1 = (const float*)d_in[3];
  const float* W2 = (const float*)d_in[4];
  const float* b2 = (const float*)d_in[5];
  const float* W3 = (const float*)d_in[6];
  const float* b3 = (const float*)d_in[7];
  float* out = (float*)d_out;

  int M = out_size / 67;               // out = unq (M*3) ++ pooled (M*64)
  float* outp = out + 3*(size_t)M;

  // workspace layout (u32 units)
  unsigned* counts = (unsigned*)d_ws;
  unsigned* rankF  = counts + NCELL;
  unsigned* rankC  = rankF + NCELL;
  unsigned* bsumF  = rankC + NCELL;
  unsigned* bsumC  = bsumF + 1024;
  unsigned* perm   = bsumC + 1024;
  unsigned* vox    = perm + NPTS;
  unsigned* pvf    = vox + NPTS;
  unsigned* pvl    = pvf + NSUB;
  u16* bp2 = (u16*)(pvl + NSUB);
  u16* bp3 = bp2 + 32768;
  u16* pmf = bp3 + 16384;
  u16* pml = pmf + (size_t)NSUB*64;
  size_t need = (size_t)((char*)(pml + (size_t)NSUB*64) - (char*)d_ws);

  hipMemsetAsync(counts, 0, NCELL*sizeof(unsigned), stream);

  if (ws_size >= need){
    // ---- sorted single-pass path: MLP + fused segmented-max pooling ----
    k_count      <<<(NPTS+255)/256, 256, 0, stream>>>(xy, counts);
    k_pack       <<<192, 256, 0, stream>>>(W2, W3, bp2, bp3);
    k_scan2      <<<SCAN_BLK, 256, 0, stream>>>(counts, rankF, rankC, bsumF, bsumC);
    k_scan_bsum2 <<<1, 1024, 0, stream>>>(bsumF, bsumC);
    k_emit2      <<<NCELL/256, 256, 0, stream>>>(counts, rankF, rankC, bsumF, bsumC, out);
    k_scatterp   <<<(NPTS+255)/256, 256, 0, stream>>>(xy, rankC, rankF, perm, vox);
    k_mlpp       <<<GRIDP, 256, 0, stream>>>(pt, perm, vox, bp2, bp3, W1, b1, b2, b3,
                                             outp, pvf, pvl, pmf, pml);
    k_fixup      <<<NSUB/4, 256, 0, stream>>>(pvf, pvl, pmf, pml, outp);
  } else {
    // ---- fallback: fkey atomicMax path ----
    unsigned* pooled = (unsigned*)outp;
    int n_pooled = M * 64;
    k_count      <<<(NPTS+255)/256, 256, 0, stream>>>(xy, counts);
    k_pack       <<<192, 256, 0, stream>>>(W2, W3, bp2, bp3);
    k_scan2      <<<SCAN_BLK, 256, 0, stream>>>(counts, rankF, rankC, bsumF, bsumC);
    k_scan_bsum2 <<<1, 1024, 0, stream>>>(bsumF, bsumC);
    k_emit2      <<<NCELL/256, 256, 0, stream>>>(counts, rankF, rankC, bsumF, bsumC, out);
    k_init_pooled<<<2048, 256, 0, stream>>>(pooled, n_pooled);
    k_mlp_atomic <<<NPTS/64, 256, 0, stream>>>(pt, xy, W1, b1, bp2, b2, bp3, b3,
                                               rankF, pooled);
    k_decode     <<<2048, 256, 0, stream>>>(pooled, n_pooled);
  }
}